// Round 10
// baseline (482.693 us; speedup 1.0000x reference)
//
#include <hip/hip_runtime.h>
#include <cstddef>
#include <cstdint>

#define NB 4
#define CC 256
#define LL 4096
#define NG 32
#define CPG 8
#define NH 4
#define DH 64
#define NSPLIT 4
#define PSPLIT 4194304   // fp16 partial-O elements per split: 16*4096*64

static constexpr float EPSV  = 1e-5f;
static constexpr float SCALE_Q = 0.125f * 1.4426950408889634f; // dh^-0.5 * log2(e)

typedef __attribute__((ext_vector_type(8))) short bf16x8;
typedef __attribute__((ext_vector_type(4))) float f32x4;
typedef _Float16 f16x8 __attribute__((ext_vector_type(8)));
typedef _Float16 f16x4 __attribute__((ext_vector_type(4)));
typedef __fp16  h16x2 __attribute__((ext_vector_type(2)));   // cvt_pkrtz native type

__device__ __forceinline__ short f2bf(float f) {
  unsigned u = __float_as_uint(f);
  unsigned r = (u + 0x7fffu + ((u >> 16) & 1u)) >> 16;
  return (short)r;
}
__device__ __forceinline__ short f2h(float f) {
  union { _Float16 h; short s; } u;
  u.h = (_Float16)f;
  return u.s;
}
// element offset of 16B chunk (8 elems) with XOR swizzle: row stride 64 elems
__device__ __forceinline__ int sw(int row, int chunk) {
  return row * 64 + ((chunk ^ (row & 7)) * 8);
}

// ---------------- GroupNorm -> xnT  +  weight convert (merged) ----------------
// blocks 0..127: gn for (n,g). blocks 128..255: weight fp32->bf16/f16.
__global__ __launch_bounds__(256) void gnw_kernel(
    const float* __restrict__ x, const float* __restrict__ gamma,
    const float* __restrict__ beta, short* __restrict__ xnT,
    const float* __restrict__ Wq, const float* __restrict__ Wk,
    const float* __restrict__ Wv, const float* __restrict__ Wp,
    short* __restrict__ Wb) {
  if (blockIdx.x >= 128) {
    const int bb = blockIdx.x - 128;
    const int which = bb >> 5;
    const float* src = (which == 0) ? Wq : (which == 1) ? Wk : (which == 2) ? Wv : Wp;
    const int base = (bb & 31) * 2048 + threadIdx.x * 8;
    const float4 v0 = *(const float4*)(src + base);
    const float4 v1 = *(const float4*)(src + base + 4);
    short ob[8] __attribute__((aligned(16)));
    if (which < 3) {
      ob[0] = f2bf(v0.x); ob[1] = f2bf(v0.y); ob[2] = f2bf(v0.z); ob[3] = f2bf(v0.w);
      ob[4] = f2bf(v1.x); ob[5] = f2bf(v1.y); ob[6] = f2bf(v1.z); ob[7] = f2bf(v1.w);
    } else {
      ob[0] = f2h(v0.x); ob[1] = f2h(v0.y); ob[2] = f2h(v0.z); ob[3] = f2h(v0.w);
      ob[4] = f2h(v1.x); ob[5] = f2h(v1.y); ob[6] = f2h(v1.z); ob[7] = f2h(v1.w);
    }
    *(uint4*)(Wb + which * 65536 + base) = *(const uint4*)ob;
    return;
  }
  const int blk = blockIdx.x;
  const int n = blk >> 5, g = blk & 31;
  const size_t base = ((size_t)n * CC + (size_t)g * CPG) * LL;
  const float* xp = x + base;
  const int NE = CPG * LL;

  float s = 0.f, ss = 0.f;
  for (int i = threadIdx.x * 4; i < NE; i += 256 * 4) {
    float4 v = *(const float4*)(xp + i);
    s  += v.x + v.y + v.z + v.w;
    ss += v.x * v.x + v.y * v.y + v.z * v.z + v.w * v.w;
  }
  #pragma unroll
  for (int off = 32; off; off >>= 1) {
    s  += __shfl_down(s, off);
    ss += __shfl_down(ss, off);
  }
  __shared__ float r1[4], r2[4], stat[2];
  const int wid = threadIdx.x >> 6, lane = threadIdx.x & 63;
  if (lane == 0) { r1[wid] = s; r2[wid] = ss; }
  __syncthreads();
  if (threadIdx.x == 0) {
    float S = 0.f, SS = 0.f;
    #pragma unroll
    for (int w = 0; w < 4; ++w) { S += r1[w]; SS += r2[w]; }
    float mean = S / NE;
    float var  = SS / NE - mean * mean;
    stat[0] = mean;
    stat[1] = rsqrtf(var + EPSV);
  }
  __syncthreads();
  const float mean = stat[0], rstd = stat[1];
  float scl[8], shf[8];
  #pragma unroll
  for (int cc = 0; cc < 8; ++cc) {
    const float gm = gamma[g * CPG + cc];
    scl[cc] = rstd * gm;
    shf[cc] = beta[g * CPG + cc] - mean * rstd * gm;
  }
  for (int j = 0; j < 4; ++j) {
    const int l = j * 1024 + threadIdx.x * 4;
    float4 vv[8];
    #pragma unroll
    for (int cc = 0; cc < 8; ++cc)
      vv[cc] = *(const float4*)(xp + (size_t)cc * LL + l);
    short ob[4][8] __attribute__((aligned(16)));
    #pragma unroll
    for (int cc = 0; cc < 8; ++cc) {
      ob[0][cc] = f2bf(vv[cc].x * scl[cc] + shf[cc]);
      ob[1][cc] = f2bf(vv[cc].y * scl[cc] + shf[cc]);
      ob[2][cc] = f2bf(vv[cc].z * scl[cc] + shf[cc]);
      ob[3][cc] = f2bf(vv[cc].w * scl[cc] + shf[cc]);
    }
    short* op = xnT + ((size_t)n * LL + l) * CC + g * CPG;
    #pragma unroll
    for (int ii = 0; ii < 4; ++ii)
      *(uint4*)(op + (size_t)ii * CC) = *(const uint4*)ob[ii];
  }
}

// ---------------- QKV MFMA GEMM ----------------
// Qt/Kt bf16 [n,h][l][d] (Q scaled by log2e/8). Vo f16 [n,h][d][l].
__global__ __launch_bounds__(256) void qkv_gemm(
    const short* __restrict__ xnT, const short* __restrict__ Wqb,
    const short* __restrict__ Wkb, const short* __restrict__ Wvb,
    short* __restrict__ Qt, short* __restrict__ Kt, _Float16* __restrict__ Vo) {
  const int lt = blockIdx.x, ot = blockIdx.y;
  const int n = lt >> 6, l0 = (lt & 63) << 6;
  const int wave = threadIdx.x >> 6, lane = threadIdx.x & 63;
  const int lq = lane & 15, quad = lane >> 4;

  const int orow = ot * 64 + wave * 16 + lq;
  const short* wqp = Wqb + orow * CC + quad * 8;
  const short* wkp = Wkb + orow * CC + quad * 8;
  const short* wvp = Wvb + orow * CC + quad * 8;
  const short* xp  = xnT + ((size_t)(n * LL + l0) + lq) * CC + quad * 8;

  const f32x4 z = {0.f, 0.f, 0.f, 0.f};
  f32x4 aq[4] = {z, z, z, z}, ak[4] = {z, z, z, z}, av[4] = {z, z, z, z};

  #pragma unroll
  for (int c0 = 0; c0 < 256; c0 += 32) {
    const bf16x8 fq = *(const bf16x8*)(wqp + c0);
    const bf16x8 fk = *(const bf16x8*)(wkp + c0);
    const bf16x8 fv = *(const bf16x8*)(wvp + c0);
    #pragma unroll
    for (int n0 = 0; n0 < 4; ++n0) {
      const bf16x8 fb = *(const bf16x8*)(xp + (size_t)(n0 * 16) * CC + c0);
      aq[n0] = __builtin_amdgcn_mfma_f32_16x16x32_bf16(fq, fb, aq[n0], 0, 0, 0);
      ak[n0] = __builtin_amdgcn_mfma_f32_16x16x32_bf16(fk, fb, ak[n0], 0, 0, 0);
      av[n0] = __builtin_amdgcn_mfma_f32_16x16x32_bf16(fv, fb, av[n0], 0, 0, 0);
    }
  }

  const size_t hb = (size_t)(n * NH + ot);
  #pragma unroll
  for (int n0 = 0; n0 < 4; ++n0)
    #pragma unroll
    for (int r = 0; r < 4; ++r)
      Vo[(hb * DH + wave * 16 + quad * 4 + r) * LL + l0 + n0 * 16 + lq] =
          (_Float16)av[n0][r];
  __shared__ short qt_lds[64][72], kt_lds[64][72];
  #pragma unroll
  for (int n0 = 0; n0 < 4; ++n0)
    #pragma unroll
    for (int r = 0; r < 4; ++r) {
      qt_lds[n0 * 16 + lq][wave * 16 + quad * 4 + r] = f2bf(aq[n0][r] * SCALE_Q);
      kt_lds[n0 * 16 + lq][wave * 16 + quad * 4 + r] = f2bf(ak[n0][r]);
    }
  __syncthreads();
  #pragma unroll
  for (int i = 0; i < 2; ++i) {
    const int u = threadIdx.x + i * 256;
    const int row = u >> 3, ch = u & 7;
    *(uint4*)(Qt + (hb * LL + l0 + row) * DH + ch * 8) = *(const uint4*)&qt_lds[row][ch * 8];
    *(uint4*)(Kt + (hb * LL + l0 + row) * DH + ch * 8) = *(const uint4*)&kt_lds[row][ch * 8];
  }
}

// ---------------- MFMA flash attention v7: 64 q/wave, k-split=4 ----------------
// grid (LL/256, NH*4, NB) = 1024 blocks (4/CU, 4 waves/SIMD), block 256.
__global__ __launch_bounds__(256, 4) void attn_mfma_kernel(
    const short* __restrict__ Qt, const short* __restrict__ Kt,
    const _Float16* __restrict__ Vb, _Float16* __restrict__ Opart,
    float* __restrict__ lpart) {
  __shared__ __align__(16) short    k_lds[2][64 * 64];   // 8 KB each, swizzled
  __shared__ __align__(16) _Float16 v_lds[2][64 * 64];   // 8 KB each, swizzled+permuted

  const int t = threadIdx.x;
  const int wave = t >> 6, lane = t & 63;
  const int lq = lane & 15, quad = lane >> 4;
  const int l0 = blockIdx.x * 256;
  const int h = blockIdx.y >> 2, split = blockIdx.y & 3;
  const int n = blockIdx.z;
  const int kbase = split * 1024;
  const int R = n * NH + h;
  const size_t hb = (size_t)R * (size_t)LL * DH;
  const short* const Kp = Kt + hb;      // [key][d] bf16
  const _Float16* const Vp = Vb + hb;   // [d][key] f16

  // Q B-frags: B[n=q][k=d] — wave's 64 q rows
  const int qbase = l0 + wave * 64;
  bf16x8 qb[4][2];
  #pragma unroll
  for (int qf = 0; qf < 4; ++qf)
    #pragma unroll
    for (int c = 0; c < 2; ++c)
      qb[qf][c] = *(const bf16x8*)(Qt + hb + (size_t)(qbase + qf * 16 + lq) * DH + c * 32 + quad * 8);

  const f32x4 z = {0.f, 0.f, 0.f, 0.f};
  f32x4 o[4][4] = {{z, z, z, z}, {z, z, z, z}, {z, z, z, z}, {z, z, z, z}};
  f32x4 ol[4] = {z, z, z, z};

  f16x8 ones8;
  #pragma unroll
  for (int i = 0; i < 8; ++i) ones8[i] = (_Float16)1.0f;

  const int srow = t >> 3, sch = t & 7;   // staging: rows 0..31(+32), chunk 0..7
  const int vgo = 32 * (sch >> 2) + 4 * (sch & 3);  // permuted key offset (lo half)

  // stage tile 0
  {
    *(uint4*)&k_lds[0][sw(srow, sch)]      = *(const uint4*)(Kp + (size_t)(kbase + srow) * DH + sch * 8);
    *(uint4*)&k_lds[0][sw(32 + srow, sch)] = *(const uint4*)(Kp + (size_t)(kbase + 32 + srow) * DH + sch * 8);
    const _Float16* vg0 = Vp + (size_t)srow * LL + kbase + vgo;
    const _Float16* vg1 = Vp + (size_t)(32 + srow) * LL + kbase + vgo;
    uint2 a = *(const uint2*)vg0, b = *(const uint2*)(vg0 + 16);
    *(uint4*)&v_lds[0][sw(srow, sch)] = make_uint4(a.x, a.y, b.x, b.y);
    a = *(const uint2*)vg1; b = *(const uint2*)(vg1 + 16);
    *(uint4*)&v_lds[0][sw(32 + srow, sch)] = make_uint4(a.x, a.y, b.x, b.y);
  }
  __syncthreads();

  for (int kt = 0; kt < 16; ++kt) {
    const int cur = kt & 1;
    // prefetch next tile into regs
    uint4 kpre[2]; uint2 vpre[4];
    if (kt < 15) {
      const int kpos = kbase + (kt + 1) * 64;
      kpre[0] = *(const uint4*)(Kp + (size_t)(kpos + srow) * DH + sch * 8);
      kpre[1] = *(const uint4*)(Kp + (size_t)(kpos + 32 + srow) * DH + sch * 8);
      const _Float16* vg0 = Vp + (size_t)srow * LL + kpos + vgo;
      const _Float16* vg1 = Vp + (size_t)(32 + srow) * LL + kpos + vgo;
      vpre[0] = *(const uint2*)vg0;
      vpre[1] = *(const uint2*)(vg0 + 16);
      vpre[2] = *(const uint2*)vg1;
      vpre[3] = *(const uint2*)(vg1 + 16);
    }
    const short* kb = k_lds[cur];
    const _Float16* vbuf = v_lds[cur];

    // ---- S^T = K·Q^T (bf16), p = exp2(s) -> f16 pack directly into A-frags ----
    union PU { f16x4 h4[2]; f16x8 h8; } af[2][4];
    #pragma unroll
    for (int mf = 0; mf < 4; ++mf) {
      const bf16x8 ka0 = *(const bf16x8*)&kb[sw(mf * 16 + lq, quad)];
      const bf16x8 ka1 = *(const bf16x8*)&kb[sw(mf * 16 + lq, 4 + quad)];
      #pragma unroll
      for (int qf = 0; qf < 4; ++qf) {
        f32x4 zz = {0.f, 0.f, 0.f, 0.f};
        zz = __builtin_amdgcn_mfma_f32_16x16x32_bf16(ka0, qb[qf][0], zz, 0, 0, 0);
        zz = __builtin_amdgcn_mfma_f32_16x16x32_bf16(ka1, qb[qf][1], zz, 0, 0, 0);
        union { h16x2 h2[2]; f16x4 h4; } u;
        u.h2[0] = __builtin_amdgcn_cvt_pkrtz(__builtin_amdgcn_exp2f(zz[0]),
                                             __builtin_amdgcn_exp2f(zz[1]));
        u.h2[1] = __builtin_amdgcn_cvt_pkrtz(__builtin_amdgcn_exp2f(zz[2]),
                                             __builtin_amdgcn_exp2f(zz[3]));
        af[mf >> 1][qf].h4[mf & 1] = u.h4;
      }
    }

    // ---- l-sum via ones-MFMA: D rows == o rows, in-lane ----
    #pragma unroll
    for (int qf = 0; qf < 4; ++qf) {
      ol[qf] = __builtin_amdgcn_mfma_f32_16x16x32_f16(af[0][qf].h8, ones8, ol[qf], 0, 0, 0);
      ol[qf] = __builtin_amdgcn_mfma_f32_16x16x32_f16(af[1][qf].h8, ones8, ol[qf], 0, 0, 0);
    }

    // ---- O += P·V: b128 V-frags, 0-conflict pattern ----
    #pragma unroll
    for (int df = 0; df < 4; ++df)
      #pragma unroll
      for (int cc = 0; cc < 2; ++cc) {
        const f16x8 vb8 = *(const f16x8*)&vbuf[sw(df * 16 + lq, cc * 4 + quad)];
        #pragma unroll
        for (int qf = 0; qf < 4; ++qf)
          o[qf][df] = __builtin_amdgcn_mfma_f32_16x16x32_f16(af[cc][qf].h8, vb8, o[qf][df], 0, 0, 0);
      }

    // ---- write prefetched tile to other buffer ----
    if (kt < 15) {
      const int nxt = 1 - cur;
      *(uint4*)&k_lds[nxt][sw(srow, sch)]      = kpre[0];
      *(uint4*)&k_lds[nxt][sw(32 + srow, sch)] = kpre[1];
      *(uint4*)&v_lds[nxt][sw(srow, sch)]      = make_uint4(vpre[0].x, vpre[0].y, vpre[1].x, vpre[1].y);
      *(uint4*)&v_lds[nxt][sw(32 + srow, sch)] = make_uint4(vpre[2].x, vpre[2].y, vpre[3].x, vpre[3].y);
      __syncthreads();
    }
  }

  // ---- epilogue: store partial l (rows match in-lane) + raw fp16 partial O ----
  const size_t pb = ((size_t)split * 16 + R) * (size_t)LL * DH;
  #pragma unroll
  for (int qf = 0; qf < 4; ++qf) {
    if (lq == 0) {
      #pragma unroll
      for (int r = 0; r < 4; ++r)
        lpart[((size_t)split * 16 + R) * LL + qbase + qf * 16 + quad * 4 + r] = ol[qf][r];
    }
    #pragma unroll
    for (int df = 0; df < 4; ++df)
      #pragma unroll
      for (int r = 0; r < 4; ++r) {
        const int q = qbase + qf * 16 + quad * 4 + r;
        Opart[pb + (size_t)q * DH + df * 16 + lq] = (_Float16)o[qf][df][r];
      }
  }
}

// ---------------- output projection (f16 MFMA, fused 4-way normalize, 2 o-tiles) --------
__global__ __launch_bounds__(256) void proj_gemm(
    const _Float16* __restrict__ Opart, const float* __restrict__ lpart,
    const _Float16* __restrict__ Wpf, const float* __restrict__ bp,
    float* __restrict__ out) {
  const int lt = blockIdx.x, ot2 = blockIdx.y;   // ot2 covers 128 output channels
  const int n = lt >> 6, l0 = (lt & 63) << 6;
  const int wave = threadIdx.x >> 6, lane = threadIdx.x & 63;
  const int lq = lane & 15, quad = lane >> 4;

  const _Float16* wpp0 = Wpf + (ot2 * 128 + wave * 16 + lq) * CC + quad * 8;
  const _Float16* wpp1 = wpp0 + 64 * CC;

  // per-(n0,h) 1/l as f16 (l = sum of 4 split partials)
  _Float16 invl[4][4];
  #pragma unroll
  for (int n0 = 0; n0 < 4; ++n0) {
    const int q = l0 + n0 * 16 + lq;
    #pragma unroll
    for (int h = 0; h < 4; ++h) {
      const size_t rr = (size_t)(n * NH + h) * LL + q;
      float lsum = 0.f;
      #pragma unroll
      for (int s = 0; s < NSPLIT; ++s) lsum += lpart[rr + (size_t)s * 16 * LL];
      invl[n0][h] = (_Float16)(1.0f / lsum);
    }
  }

  const f32x4 z = {0.f, 0.f, 0.f, 0.f};
  f32x4 acc[2][4] = {{z, z, z, z}, {z, z, z, z}};
  #pragma unroll
  for (int c0 = 0; c0 < 256; c0 += 32) {
    const int h = c0 >> 6;
    const int d0 = (c0 & 63) + quad * 8;
    const f16x8 fa0 = *(const f16x8*)(wpp0 + c0);
    const f16x8 fa1 = *(const f16x8*)(wpp1 + c0);
    #pragma unroll
    for (int n0 = 0; n0 < 4; ++n0) {
      const int q = l0 + n0 * 16 + lq;
      const size_t e = ((size_t)(n * NH + h) * LL + q) * DH + d0;
      const f16x8 b0 = *(const f16x8*)(Opart + e);
      const f16x8 b1 = *(const f16x8*)(Opart + e + PSPLIT);
      const f16x8 b2 = *(const f16x8*)(Opart + e + 2 * (size_t)PSPLIT);
      const f16x8 b3 = *(const f16x8*)(Opart + e + 3 * (size_t)PSPLIT);
      f16x8 sc8;
      #pragma unroll
      for (int i = 0; i < 8; ++i) sc8[i] = invl[n0][h];
      const f16x8 fb = ((b0 + b1) + (b2 + b3)) * sc8;
      acc[0][n0] = __builtin_amdgcn_mfma_f32_16x16x32_f16(fa0, fb, acc[0][n0], 0, 0, 0);
      acc[1][n0] = __builtin_amdgcn_mfma_f32_16x16x32_f16(fa1, fb, acc[1][n0], 0, 0, 0);
    }
  }
  #pragma unroll
  for (int w = 0; w < 2; ++w)
    #pragma unroll
    for (int r = 0; r < 4; ++r) {
      const int oo = ot2 * 128 + w * 64 + wave * 16 + quad * 4 + r;
      const float bias = bp[oo];
      #pragma unroll
      for (int n0 = 0; n0 < 4; ++n0)
        out[((size_t)n * CC + oo) * LL + l0 + n0 * 16 + lq] = acc[w][n0][r] + bias;
    }
}

extern "C" void kernel_launch(void* const* d_in, const int* in_sizes, int n_in,
                              void* d_out, int out_size, void* d_ws, size_t ws_size,
                              hipStream_t stream) {
  const float* x     = (const float*)d_in[0];
  const float* gamma = (const float*)d_in[1];
  const float* beta  = (const float*)d_in[2];
  const float* Wq    = (const float*)d_in[3];
  const float* Wk    = (const float*)d_in[4];
  const float* Wv    = (const float*)d_in[5];
  const float* Wp    = (const float*)d_in[6];
  const float* bp    = (const float*)d_in[7];
  float* out = (float*)d_out;

  const size_t S = (size_t)NB * CC * LL;  // 4,194,304
  // Layout (ws): Qt | Kt | Vo | Wb | lpart | Opart(4 splits, 33.5 MB)
  // xnT aliases the head of Opart: xnT dies when qkv finishes; Opart is born in attn.
  short*     Qt  = (short*)d_ws;                    // bf16 [n,h][l][d]
  short*     Kt  = Qt + S;
  _Float16*  Vo  = (_Float16*)(Kt + S);             // f16 [n,h][d][l]
  short*     Wb  = (short*)(Vo + S);                // 4 x 65536
  float*     lpart = (float*)(Wb + 4 * 65536);      // 4 x 16 x 4096 fp32 = 1 MB
  _Float16*  Opart = (_Float16*)(lpart + NSPLIT * 16 * LL); // 4 x 8 MB fp16
  short*     xnT = (short*)Opart;                   // bf16 [n][l][c], aliased

  gnw_kernel <<<256,                  256, 0, stream>>>(x, gamma, beta, xnT,
                                                        Wq, Wk, Wv, Wp, Wb);
  qkv_gemm   <<<dim3(256, 4),         256, 0, stream>>>(xnT, Wb, Wb + 65536, Wb + 131072, Qt, Kt, Vo);
  attn_mfma_kernel<<<dim3(LL/256, NH*NSPLIT, NB), 256, 0, stream>>>(Qt, Kt, Vo, Opart, lpart);
  proj_gemm  <<<dim3(256, 2),         256, 0, stream>>>(Opart, lpart,
                 (const _Float16*)(Wb + 196608), bp, out);
}

// Round 11
// 225.337 us; speedup vs baseline: 2.1421x; 2.1421x over previous
//
#include <hip/hip_runtime.h>
#include <cstddef>
#include <cstdint>

#define NB 4
#define CC 256
#define LL 4096
#define NG 32
#define CPG 8
#define NH 4
#define DH 64
#define PSPLIT 4194304   // fp16 partial-O elements per split: 16*4096*64

static constexpr float EPSV  = 1e-5f;
static constexpr float SCALE_Q = 0.125f * 1.4426950408889634f; // dh^-0.5 * log2(e)

typedef __attribute__((ext_vector_type(8))) short bf16x8;
typedef __attribute__((ext_vector_type(4))) float f32x4;
typedef _Float16 f16x8 __attribute__((ext_vector_type(8)));
typedef _Float16 f16x4 __attribute__((ext_vector_type(4)));
typedef __fp16  h16x2 __attribute__((ext_vector_type(2)));   // cvt_pkrtz native type

__device__ __forceinline__ short f2bf(float f) {
  unsigned u = __float_as_uint(f);
  unsigned r = (u + 0x7fffu + ((u >> 16) & 1u)) >> 16;
  return (short)r;
}
__device__ __forceinline__ short f2h(float f) {
  union { _Float16 h; short s; } u;
  u.h = (_Float16)f;
  return u.s;
}
// element offset of 16B chunk (8 elems) with XOR swizzle: row stride 64 elems
__device__ __forceinline__ int sw(int row, int chunk) {
  return row * 64 + ((chunk ^ (row & 7)) * 8);
}

// ---------------- GroupNorm -> xnT  +  weight convert (merged) ----------------
// blocks 0..127: gn for (n,g). blocks 128..255: weight fp32->bf16/f16.
__global__ __launch_bounds__(256) void gnw_kernel(
    const float* __restrict__ x, const float* __restrict__ gamma,
    const float* __restrict__ beta, short* __restrict__ xnT,
    const float* __restrict__ Wq, const float* __restrict__ Wk,
    const float* __restrict__ Wv, const float* __restrict__ Wp,
    short* __restrict__ Wb) {
  if (blockIdx.x >= 128) {
    const int bb = blockIdx.x - 128;
    const int which = bb >> 5;
    const float* src = (which == 0) ? Wq : (which == 1) ? Wk : (which == 2) ? Wv : Wp;
    const int base = (bb & 31) * 2048 + threadIdx.x * 8;
    const float4 v0 = *(const float4*)(src + base);
    const float4 v1 = *(const float4*)(src + base + 4);
    short ob[8] __attribute__((aligned(16)));
    if (which < 3) {
      ob[0] = f2bf(v0.x); ob[1] = f2bf(v0.y); ob[2] = f2bf(v0.z); ob[3] = f2bf(v0.w);
      ob[4] = f2bf(v1.x); ob[5] = f2bf(v1.y); ob[6] = f2bf(v1.z); ob[7] = f2bf(v1.w);
    } else {
      ob[0] = f2h(v0.x); ob[1] = f2h(v0.y); ob[2] = f2h(v0.z); ob[3] = f2h(v0.w);
      ob[4] = f2h(v1.x); ob[5] = f2h(v1.y); ob[6] = f2h(v1.z); ob[7] = f2h(v1.w);
    }
    *(uint4*)(Wb + which * 65536 + base) = *(const uint4*)ob;
    return;
  }
  const int blk = blockIdx.x;
  const int n = blk >> 5, g = blk & 31;
  const size_t base = ((size_t)n * CC + (size_t)g * CPG) * LL;
  const float* xp = x + base;
  const int NE = CPG * LL;

  float s = 0.f, ss = 0.f;
  for (int i = threadIdx.x * 4; i < NE; i += 256 * 4) {
    float4 v = *(const float4*)(xp + i);
    s  += v.x + v.y + v.z + v.w;
    ss += v.x * v.x + v.y * v.y + v.z * v.z + v.w * v.w;
  }
  #pragma unroll
  for (int off = 32; off; off >>= 1) {
    s  += __shfl_down(s, off);
    ss += __shfl_down(ss, off);
  }
  __shared__ float r1[4], r2[4], stat[2];
  const int wid = threadIdx.x >> 6, lane = threadIdx.x & 63;
  if (lane == 0) { r1[wid] = s; r2[wid] = ss; }
  __syncthreads();
  if (threadIdx.x == 0) {
    float S = 0.f, SS = 0.f;
    #pragma unroll
    for (int w = 0; w < 4; ++w) { S += r1[w]; SS += r2[w]; }
    float mean = S / NE;
    float var  = SS / NE - mean * mean;
    stat[0] = mean;
    stat[1] = rsqrtf(var + EPSV);
  }
  __syncthreads();
  const float mean = stat[0], rstd = stat[1];
  float scl[8], shf[8];
  #pragma unroll
  for (int cc = 0; cc < 8; ++cc) {
    const float gm = gamma[g * CPG + cc];
    scl[cc] = rstd * gm;
    shf[cc] = beta[g * CPG + cc] - mean * rstd * gm;
  }
  for (int j = 0; j < 4; ++j) {
    const int l = j * 1024 + threadIdx.x * 4;
    float4 vv[8];
    #pragma unroll
    for (int cc = 0; cc < 8; ++cc)
      vv[cc] = *(const float4*)(xp + (size_t)cc * LL + l);
    short ob[4][8] __attribute__((aligned(16)));
    #pragma unroll
    for (int cc = 0; cc < 8; ++cc) {
      ob[0][cc] = f2bf(vv[cc].x * scl[cc] + shf[cc]);
      ob[1][cc] = f2bf(vv[cc].y * scl[cc] + shf[cc]);
      ob[2][cc] = f2bf(vv[cc].z * scl[cc] + shf[cc]);
      ob[3][cc] = f2bf(vv[cc].w * scl[cc] + shf[cc]);
    }
    short* op = xnT + ((size_t)n * LL + l) * CC + g * CPG;
    #pragma unroll
    for (int ii = 0; ii < 4; ++ii)
      *(uint4*)(op + (size_t)ii * CC) = *(const uint4*)ob[ii];
  }
}

// ---------------- QKV MFMA GEMM ----------------
// Qt/Kt bf16 [n,h][l][d] (Q scaled by log2e/8). Vo f16 [n,h][d][l].
__global__ __launch_bounds__(256) void qkv_gemm(
    const short* __restrict__ xnT, const short* __restrict__ Wqb,
    const short* __restrict__ Wkb, const short* __restrict__ Wvb,
    short* __restrict__ Qt, short* __restrict__ Kt, _Float16* __restrict__ Vo) {
  const int lt = blockIdx.x, ot = blockIdx.y;
  const int n = lt >> 6, l0 = (lt & 63) << 6;
  const int wave = threadIdx.x >> 6, lane = threadIdx.x & 63;
  const int lq = lane & 15, quad = lane >> 4;

  const int orow = ot * 64 + wave * 16 + lq;
  const short* wqp = Wqb + orow * CC + quad * 8;
  const short* wkp = Wkb + orow * CC + quad * 8;
  const short* wvp = Wvb + orow * CC + quad * 8;
  const short* xp  = xnT + ((size_t)(n * LL + l0) + lq) * CC + quad * 8;

  const f32x4 z = {0.f, 0.f, 0.f, 0.f};
  f32x4 aq[4] = {z, z, z, z}, ak[4] = {z, z, z, z}, av[4] = {z, z, z, z};

  #pragma unroll
  for (int c0 = 0; c0 < 256; c0 += 32) {
    const bf16x8 fq = *(const bf16x8*)(wqp + c0);
    const bf16x8 fk = *(const bf16x8*)(wkp + c0);
    const bf16x8 fv = *(const bf16x8*)(wvp + c0);
    #pragma unroll
    for (int n0 = 0; n0 < 4; ++n0) {
      const bf16x8 fb = *(const bf16x8*)(xp + (size_t)(n0 * 16) * CC + c0);
      aq[n0] = __builtin_amdgcn_mfma_f32_16x16x32_bf16(fq, fb, aq[n0], 0, 0, 0);
      ak[n0] = __builtin_amdgcn_mfma_f32_16x16x32_bf16(fk, fb, ak[n0], 0, 0, 0);
      av[n0] = __builtin_amdgcn_mfma_f32_16x16x32_bf16(fv, fb, av[n0], 0, 0, 0);
    }
  }

  const size_t hb = (size_t)(n * NH + ot);
  #pragma unroll
  for (int n0 = 0; n0 < 4; ++n0)
    #pragma unroll
    for (int r = 0; r < 4; ++r)
      Vo[(hb * DH + wave * 16 + quad * 4 + r) * LL + l0 + n0 * 16 + lq] =
          (_Float16)av[n0][r];
  __shared__ short qt_lds[64][72], kt_lds[64][72];
  #pragma unroll
  for (int n0 = 0; n0 < 4; ++n0)
    #pragma unroll
    for (int r = 0; r < 4; ++r) {
      qt_lds[n0 * 16 + lq][wave * 16 + quad * 4 + r] = f2bf(aq[n0][r] * SCALE_Q);
      kt_lds[n0 * 16 + lq][wave * 16 + quad * 4 + r] = f2bf(ak[n0][r]);
    }
  __syncthreads();
  #pragma unroll
  for (int i = 0; i < 2; ++i) {
    const int u = threadIdx.x + i * 256;
    const int row = u >> 3, ch = u & 7;
    *(uint4*)(Qt + (hb * LL + l0 + row) * DH + ch * 8) = *(const uint4*)&qt_lds[row][ch * 8];
    *(uint4*)(Kt + (hb * LL + l0 + row) * DH + ch * 8) = *(const uint4*)&kt_lds[row][ch * 8];
  }
}

// ---------------- MFMA flash attention v8: 32 q/wave, k-split=2, 4 blocks/CU ----
// grid (LL/128, NH*2, NB) = 1024 blocks, block 256 (4 waves).
// Live regs ~110 <= 128 -> no spill at 4 waves/SIMD (R10 lesson).
__global__ __launch_bounds__(256, 4) void attn_mfma_kernel(
    const short* __restrict__ Qt, const short* __restrict__ Kt,
    const _Float16* __restrict__ Vb, _Float16* __restrict__ Opart,
    float* __restrict__ lpart) {
  __shared__ __align__(16) short    k_lds[2][64 * 64];   // 8 KB each, swizzled
  __shared__ __align__(16) _Float16 v_lds[2][64 * 64];   // 8 KB each, swizzled+permuted

  const int t = threadIdx.x;
  const int wave = t >> 6, lane = t & 63;
  const int lq = lane & 15, quad = lane >> 4;
  const int l0 = blockIdx.x * 128;
  const int h = blockIdx.y >> 1, split = blockIdx.y & 1;
  const int n = blockIdx.z;
  const int kbase = split * 2048;
  const int R = n * NH + h;
  const size_t hb = (size_t)R * (size_t)LL * DH;
  const short* const Kp = Kt + hb;      // [key][d] bf16
  const _Float16* const Vp = Vb + hb;   // [d][key] f16

  // Q B-frags: B[n=q][k=d] — wave's 32 q rows
  const int qbase = l0 + wave * 32;
  bf16x8 qb[2][2];
  #pragma unroll
  for (int qf = 0; qf < 2; ++qf)
    #pragma unroll
    for (int c = 0; c < 2; ++c)
      qb[qf][c] = *(const bf16x8*)(Qt + hb + (size_t)(qbase + qf * 16 + lq) * DH + c * 32 + quad * 8);

  const f32x4 z = {0.f, 0.f, 0.f, 0.f};
  f32x4 o[2][4] = {{z, z, z, z}, {z, z, z, z}};
  f32x4 ol[2] = {z, z};

  f16x8 ones8;
  #pragma unroll
  for (int i = 0; i < 8; ++i) ones8[i] = (_Float16)1.0f;

  const int srow = t >> 3, sch = t & 7;   // staging: rows 0..31(+32), chunk 0..7
  const int vgo = 32 * (sch >> 2) + 4 * (sch & 3);  // permuted key offset (lo half)

  // stage tile 0
  {
    *(uint4*)&k_lds[0][sw(srow, sch)]      = *(const uint4*)(Kp + (size_t)(kbase + srow) * DH + sch * 8);
    *(uint4*)&k_lds[0][sw(32 + srow, sch)] = *(const uint4*)(Kp + (size_t)(kbase + 32 + srow) * DH + sch * 8);
    const _Float16* vg0 = Vp + (size_t)srow * LL + kbase + vgo;
    const _Float16* vg1 = Vp + (size_t)(32 + srow) * LL + kbase + vgo;
    uint2 a = *(const uint2*)vg0, b = *(const uint2*)(vg0 + 16);
    *(uint4*)&v_lds[0][sw(srow, sch)] = make_uint4(a.x, a.y, b.x, b.y);
    a = *(const uint2*)vg1; b = *(const uint2*)(vg1 + 16);
    *(uint4*)&v_lds[0][sw(32 + srow, sch)] = make_uint4(a.x, a.y, b.x, b.y);
  }
  __syncthreads();

  for (int kt = 0; kt < 32; ++kt) {
    const int cur = kt & 1;
    // prefetch next tile into regs
    uint4 kpre[2]; uint2 vpre[4];
    if (kt < 31) {
      const int kpos = kbase + (kt + 1) * 64;
      kpre[0] = *(const uint4*)(Kp + (size_t)(kpos + srow) * DH + sch * 8);
      kpre[1] = *(const uint4*)(Kp + (size_t)(kpos + 32 + srow) * DH + sch * 8);
      const _Float16* vg0 = Vp + (size_t)srow * LL + kpos + vgo;
      const _Float16* vg1 = Vp + (size_t)(32 + srow) * LL + kpos + vgo;
      vpre[0] = *(const uint2*)vg0;
      vpre[1] = *(const uint2*)(vg0 + 16);
      vpre[2] = *(const uint2*)vg1;
      vpre[3] = *(const uint2*)(vg1 + 16);
    }
    const short* kb = k_lds[cur];
    const _Float16* vbuf = v_lds[cur];

    // ---- S^T = K·Q^T (bf16), p = exp2(s) -> f16 pack directly into A-frags ----
    union PU { f16x4 h4[2]; f16x8 h8; } af[2][2];
    #pragma unroll
    for (int mf = 0; mf < 4; ++mf) {
      const bf16x8 ka0 = *(const bf16x8*)&kb[sw(mf * 16 + lq, quad)];
      const bf16x8 ka1 = *(const bf16x8*)&kb[sw(mf * 16 + lq, 4 + quad)];
      #pragma unroll
      for (int qf = 0; qf < 2; ++qf) {
        f32x4 zz = {0.f, 0.f, 0.f, 0.f};
        zz = __builtin_amdgcn_mfma_f32_16x16x32_bf16(ka0, qb[qf][0], zz, 0, 0, 0);
        zz = __builtin_amdgcn_mfma_f32_16x16x32_bf16(ka1, qb[qf][1], zz, 0, 0, 0);
        union { h16x2 h2[2]; f16x4 h4; } u;
        u.h2[0] = __builtin_amdgcn_cvt_pkrtz(__builtin_amdgcn_exp2f(zz[0]),
                                             __builtin_amdgcn_exp2f(zz[1]));
        u.h2[1] = __builtin_amdgcn_cvt_pkrtz(__builtin_amdgcn_exp2f(zz[2]),
                                             __builtin_amdgcn_exp2f(zz[3]));
        af[mf >> 1][qf].h4[mf & 1] = u.h4;
      }
    }

    // ---- l-sum via ones-MFMA: D rows == o rows, in-lane ----
    #pragma unroll
    for (int qf = 0; qf < 2; ++qf) {
      ol[qf] = __builtin_amdgcn_mfma_f32_16x16x32_f16(af[0][qf].h8, ones8, ol[qf], 0, 0, 0);
      ol[qf] = __builtin_amdgcn_mfma_f32_16x16x32_f16(af[1][qf].h8, ones8, ol[qf], 0, 0, 0);
    }

    // ---- O += P·V: b128 V-frags, 0-conflict pattern ----
    #pragma unroll
    for (int df = 0; df < 4; ++df)
      #pragma unroll
      for (int cc = 0; cc < 2; ++cc) {
        const f16x8 vb8 = *(const f16x8*)&vbuf[sw(df * 16 + lq, cc * 4 + quad)];
        #pragma unroll
        for (int qf = 0; qf < 2; ++qf)
          o[qf][df] = __builtin_amdgcn_mfma_f32_16x16x32_f16(af[cc][qf].h8, vb8, o[qf][df], 0, 0, 0);
      }

    // ---- write prefetched tile to other buffer ----
    if (kt < 31) {
      const int nxt = 1 - cur;
      *(uint4*)&k_lds[nxt][sw(srow, sch)]      = kpre[0];
      *(uint4*)&k_lds[nxt][sw(32 + srow, sch)] = kpre[1];
      *(uint4*)&v_lds[nxt][sw(srow, sch)]      = make_uint4(vpre[0].x, vpre[0].y, vpre[1].x, vpre[1].y);
      *(uint4*)&v_lds[nxt][sw(32 + srow, sch)] = make_uint4(vpre[2].x, vpre[2].y, vpre[3].x, vpre[3].y);
      __syncthreads();
    }
  }

  // ---- epilogue: store partial l (rows match in-lane) + raw fp16 partial O ----
  const size_t pb = ((size_t)split * 16 + R) * (size_t)LL * DH;
  #pragma unroll
  for (int qf = 0; qf < 2; ++qf) {
    if (lq == 0) {
      #pragma unroll
      for (int r = 0; r < 4; ++r)
        lpart[((size_t)split * 16 + R) * LL + qbase + qf * 16 + quad * 4 + r] = ol[qf][r];
    }
    #pragma unroll
    for (int df = 0; df < 4; ++df)
      #pragma unroll
      for (int r = 0; r < 4; ++r) {
        const int q = qbase + qf * 16 + quad * 4 + r;
        Opart[pb + (size_t)q * DH + df * 16 + lq] = (_Float16)o[qf][df][r];
      }
  }
}

// ---------------- output projection (f16 MFMA, fused normalize, 2 o-tiles) ----------------
__global__ __launch_bounds__(256) void proj_gemm(
    const _Float16* __restrict__ Opart, const float* __restrict__ lpart,
    const _Float16* __restrict__ Wpf, const float* __restrict__ bp,
    float* __restrict__ out) {
  const int lt = blockIdx.x, ot2 = blockIdx.y;   // ot2 covers 128 output channels
  const int n = lt >> 6, l0 = (lt & 63) << 6;
  const int wave = threadIdx.x >> 6, lane = threadIdx.x & 63;
  const int lq = lane & 15, quad = lane >> 4;

  const _Float16* wpp0 = Wpf + (ot2 * 128 + wave * 16 + lq) * CC + quad * 8;
  const _Float16* wpp1 = wpp0 + 64 * CC;

  // per-(n0,h) 1/l as f16 (l = lpart split0 + split1)
  _Float16 invl[4][4];
  #pragma unroll
  for (int n0 = 0; n0 < 4; ++n0) {
    const int q = l0 + n0 * 16 + lq;
    #pragma unroll
    for (int h = 0; h < 4; ++h) {
      const size_t rr = (size_t)(n * NH + h) * LL + q;
      invl[n0][h] = (_Float16)(1.0f / (lpart[rr] + lpart[rr + 16 * (size_t)LL]));
    }
  }

  const f32x4 z = {0.f, 0.f, 0.f, 0.f};
  f32x4 acc[2][4] = {{z, z, z, z}, {z, z, z, z}};
  #pragma unroll
  for (int c0 = 0; c0 < 256; c0 += 32) {
    const int h = c0 >> 6;
    const int d0 = (c0 & 63) + quad * 8;
    const f16x8 fa0 = *(const f16x8*)(wpp0 + c0);
    const f16x8 fa1 = *(const f16x8*)(wpp1 + c0);
    #pragma unroll
    for (int n0 = 0; n0 < 4; ++n0) {
      const int q = l0 + n0 * 16 + lq;
      const size_t e = ((size_t)(n * NH + h) * LL + q) * DH + d0;
      const f16x8 b0 = *(const f16x8*)(Opart + e);
      const f16x8 b1 = *(const f16x8*)(Opart + e + PSPLIT);
      f16x8 sc8;
      #pragma unroll
      for (int i = 0; i < 8; ++i) sc8[i] = invl[n0][h];
      const f16x8 fb = (b0 + b1) * sc8;
      acc[0][n0] = __builtin_amdgcn_mfma_f32_16x16x32_f16(fa0, fb, acc[0][n0], 0, 0, 0);
      acc[1][n0] = __builtin_amdgcn_mfma_f32_16x16x32_f16(fa1, fb, acc[1][n0], 0, 0, 0);
    }
  }
  #pragma unroll
  for (int w = 0; w < 2; ++w)
    #pragma unroll
    for (int r = 0; r < 4; ++r) {
      const int oo = ot2 * 128 + w * 64 + wave * 16 + quad * 4 + r;
      const float bias = bp[oo];
      #pragma unroll
      for (int n0 = 0; n0 < 4; ++n0)
        out[((size_t)n * CC + oo) * LL + l0 + n0 * 16 + lq] = acc[w][n0][r] + bias;
    }
}

extern "C" void kernel_launch(void* const* d_in, const int* in_sizes, int n_in,
                              void* d_out, int out_size, void* d_ws, size_t ws_size,
                              hipStream_t stream) {
  const float* x     = (const float*)d_in[0];
  const float* gamma = (const float*)d_in[1];
  const float* beta  = (const float*)d_in[2];
  const float* Wq    = (const float*)d_in[3];
  const float* Wk    = (const float*)d_in[4];
  const float* Wv    = (const float*)d_in[5];
  const float* Wp    = (const float*)d_in[6];
  const float* bp    = (const float*)d_in[7];
  float* out = (float*)d_out;

  const size_t S = (size_t)NB * CC * LL;  // 4,194,304
  // Layout (ws): Qt | Kt | Vo | Wb | lpart | Opart(2 splits, 16 MB)
  // xnT aliases Opart: xnT dies when qkv finishes; Opart is born in attn.
  short*     Qt  = (short*)d_ws;                    // bf16 [n,h][l][d]
  short*     Kt  = Qt + S;
  _Float16*  Vo  = (_Float16*)(Kt + S);             // f16 [n,h][d][l]
  short*     Wb  = (short*)(Vo + S);                // 4 x 65536
  float*     lpart = (float*)(Wb + 4 * 65536);      // 2 x 16 x 4096 fp32
  _Float16*  Opart = (_Float16*)(lpart + 2 * 16 * LL); // 2 x 8 MB fp16
  short*     xnT = (short*)Opart;                   // bf16 [n][l][c], aliased

  gnw_kernel <<<256,                  256, 0, stream>>>(x, gamma, beta, xnT,
                                                        Wq, Wk, Wv, Wp, Wb);
  qkv_gemm   <<<dim3(256, 4),         256, 0, stream>>>(xnT, Wb, Wb + 65536, Wb + 131072, Qt, Kt, Vo);
  attn_mfma_kernel<<<dim3(LL/128, NH*2, NB), 256, 0, stream>>>(Qt, Kt, Vo, Opart, lpart);
  proj_gemm  <<<dim3(256, 2),         256, 0, stream>>>(Opart, lpart,
                 (const _Float16*)(Wb + 196608), bp, out);
}